// Round 3
// baseline (5432.823 us; speedup 1.0000x reference)
//
#include <hip/hip_runtime.h>

// GraphLSTM MFMA version. S=32 steps, N=65536 nodes.
// Per step: k_graph (bf16 MFMA gates [N,96]@[96,256] + LSTM pointwise + block
// sums of gh2 + LAST-BLOCK fold: reduce partials -> cell-gate step bias),
// then k_cell (bf16 MFMA gates [N,160]@[160,256], K = [dyn | gh2 | ch], with
// graph_feat folded: per-node -gh2@Wfold in K, common S@Wfold in step bias).
// h-states carried in bf16 (ws); c-states f32 (d_out slots).

#define Sx    32
#define Nx    65536
#define DYNx  32
#define GHx   64
#define MATx  32
#define CHx   64
#define OUTx  5
#define NPB   64              // nodes per block (4 waves x 16)
#define GB    (Nx / NPB)      // 1024 blocks
#define KG    96              // graph gates K: [gemb(32) | gh(64)]
#define KC    160             // cell gates K:  [dyn(32) | gh2(64) | ch(64)]

typedef __attribute__((ext_vector_type(4))) float f32x4;
typedef __attribute__((ext_vector_type(8))) short bf16x8;
typedef unsigned short ushort;
typedef unsigned int uint;

__device__ __forceinline__ float sigm(float x) {
    return __frcp_rn(1.f + __expf(-x));
}
__device__ __forceinline__ float tanh_fast(float x) {
    return fmaf(-2.f, __frcp_rn(1.f + __expf(2.f * x)), 1.f);
}
__device__ __forceinline__ ushort f2b(float x) {
    uint u = __float_as_uint(x);
    u += 0x7fffu + ((u >> 16) & 1u);   // RNE
    return (ushort)(u >> 16);
}

// ---------------- weight prep (once per launch, parallel) ----------------
__global__ __launch_bounds__(256) void k_prep(
    const float* __restrict__ Wih_g, const float* __restrict__ Whh_g,
    const float* __restrict__ bih_g, const float* __restrict__ bhh_g,
    const float* __restrict__ wgr,
    const float* __restrict__ Wih_c, const float* __restrict__ Whh_c,
    const float* __restrict__ bih_c, const float* __restrict__ bhh_c,
    ushort* __restrict__ Wg, ushort* __restrict__ Wc,
    float* __restrict__ bsum_g, float* __restrict__ bC0)
{
    const int tid = blockIdx.x * 256 + threadIdx.x;
    const int nt = gridDim.x * 256;
    for (int idx = tid; idx < 256 * KG; idx += nt) {
        int col = idx / KG, k = idx % KG;
        float v = (k < 32) ? Wih_g[col * 32 + k] : Whh_g[col * 64 + (k - 32)];
        Wg[idx] = f2b(v);
    }
    for (int idx = tid; idx < 256 * KC; idx += nt) {
        int col = idx / KC, k = idx % KC;
        float v;
        if (k < 32) v = Wih_c[col * 64 + k];
        else if (k < 96) {
            int d = k - 32; float a = 0.f;
            for (int j = 0; j < 32; ++j)
                a = fmaf(wgr[d * 32 + j], Wih_c[col * 64 + 32 + j], a);
            v = -a;   // per-node part of loo is (-gh2)
        } else v = Whh_c[col * 64 + (k - 96)];
        Wc[idx] = f2b(v);
    }
    if (tid < 256) {
        bsum_g[tid] = bih_g[tid] + bhh_g[tid];
        bC0[tid]    = bih_c[tid] + bhh_c[tid];
    }
}

__global__ __launch_bounds__(256) void k_init(
    const float* __restrict__ gh0, const float* __restrict__ ch0,
    ushort* __restrict__ ghb, ushort* __restrict__ chb,
    int* __restrict__ counters)
{
    const int i = blockIdx.x * 256 + threadIdx.x;
    ghb[i] = f2b(gh0[i]);
    chb[i] = f2b(ch0[i]);
    if (i < Sx) counters[i] = 0;   // re-zero tickets every launch (determinism)
}

// ---------------- graph LSTM step (+ folded reduce in last block) ----------
__global__ __launch_bounds__(256) void k_graph(
    const float* __restrict__ frame,               // [N][2]
    const float* __restrict__ Wge, const float* __restrict__ bge,  // [32][2],[32]
    const ushort* __restrict__ Wg,                 // [256][96] bf16
    const float* __restrict__ bsum_g,              // [256]
    float* __restrict__ gc,                        // [N][64] f32 live state
    ushort* __restrict__ ghb,                      // [N][64] bf16 live state
    float* __restrict__ ghf,                       // [N][64] f32 (written iff last)
    float* __restrict__ partials,                  // [GB][64]
    const float* __restrict__ wgr,                 // [64][32]
    const float* __restrict__ Wih_c,               // [256][64]
    const float* __restrict__ bC0,                 // [256]
    float* __restrict__ bias_c,                    // [256] (output of fold)
    int* __restrict__ ticket,                      // per-step counter
    int last)
{
    const int wave = threadIdx.x >> 6, lane = threadIdx.x & 63;
    const int c = lane & 15, g4 = lane >> 4;
    const int nbase = blockIdx.x * NPB + wave * 16;
    const int tid = threadIdx.x;

    // ---- A fragments (rows = nodes nbase+c) ----
    const int na = nbase + c;
    const float f0 = frame[2 * na], f1 = frame[2 * na + 1];
    bf16x8 a0, a1, a2;
    {
#pragma unroll
        for (int j = 0; j < 8; ++j) {
            int k = g4 * 8 + j;
            float v = fmaf(f1, Wge[2 * k + 1], fmaf(f0, Wge[2 * k], bge[k]));
            a0[j] = (short)f2b(fmaxf(v, 0.f));
        }
        a1 = *(const bf16x8*)(ghb + na * 64 + g4 * 8);
        a2 = *(const bf16x8*)(ghb + na * 64 + 32 + g4 * 8);
    }

    float hsq[4];
#pragma unroll
    for (int q = 0; q < 4; ++q) {
        f32x4 acc[4];
#pragma unroll
        for (int g = 0; g < 4; ++g) {
            acc[g] = (f32x4){0.f, 0.f, 0.f, 0.f};
            const int colb = 16 * (4 * g + q);
            const ushort* wp = Wg + (colb + c) * KG + g4 * 8;
            bf16x8 b0 = *(const bf16x8*)(wp);
            bf16x8 b1 = *(const bf16x8*)(wp + 32);
            bf16x8 b2 = *(const bf16x8*)(wp + 64);
            acc[g] = __builtin_amdgcn_mfma_f32_16x16x32_bf16(a0, b0, acc[g], 0, 0, 0);
            acc[g] = __builtin_amdgcn_mfma_f32_16x16x32_bf16(a1, b1, acc[g], 0, 0, 0);
            acc[g] = __builtin_amdgcn_mfma_f32_16x16x32_bf16(a2, b2, acc[g], 0, 0, 0);
        }
        // pointwise LSTM for dims d=16q+c, rows 4*g4+r
        const int d = 16 * q + c;
        const float bi = bsum_g[d], bf = bsum_g[64 + d],
                    bg = bsum_g[128 + d], bo = bsum_g[192 + d];
        float s_r = 0.f;
#pragma unroll
        for (int r = 0; r < 4; ++r) {
            const int n = nbase + 4 * g4 + r;
            const float ai = acc[0][r] + bi, af = acc[1][r] + bf,
                        ag = acc[2][r] + bg, ao = acc[3][r] + bo;
            const float cp = gc[n * 64 + d];
            const float c2 = fmaf(sigm(af), cp, sigm(ai) * tanh_fast(ag));
            gc[n * 64 + d] = c2;
            const float h2 = sigm(ao) * tanh_fast(c2);
            ghb[n * 64 + d] = f2b(h2);
            if (last) ghf[n * 64 + d] = h2;
            s_r += h2;
        }
        hsq[q] = s_r;
    }
    // reduce across g4 groups (rows) -> per-wave dim sums
#pragma unroll
    for (int q = 0; q < 4; ++q) {
        float v = hsq[q];
        v += __shfl_xor(v, 16);
        v += __shfl_xor(v, 32);
        hsq[q] = v;
    }
    __shared__ float wsum[4][64];
    if (g4 == 0) {
#pragma unroll
        for (int q = 0; q < 4; ++q) wsum[wave][16 * q + c] = hsq[q];
    }
    __syncthreads();
    if (tid < 64) {
        partials[blockIdx.x * 64 + tid] =
            wsum[0][tid] + wsum[1][tid] + wsum[2][tid] + wsum[3][tid];
    }

    // ---- last-block fold: reduce partials -> S -> cell-gate step bias ----
    __threadfence();            // publish partials device-wide
    __syncthreads();            // all threads' fences done before ticket
    __shared__ int slast;
    if (tid == 0) slast = (atomicAdd(ticket, 1) == GB - 1);
    __syncthreads();
    if (slast) {
        __threadfence();        // acquire: see all blocks' partials
        __shared__ float red[16][64];
        __shared__ float S[64];
        __shared__ float gsf[32];
        const int q4 = tid & 15, g = tid >> 4;   // 16 dim-groups x 16 row-groups
        f32x4 acc4 = (f32x4){0.f, 0.f, 0.f, 0.f};
        for (int b = g; b < GB; b += 16)
            acc4 += *(const f32x4*)(partials + b * 64 + q4 * 4);
        *(f32x4*)(&red[g][q4 * 4]) = acc4;
        __syncthreads();
        if (tid < 64) {
            float a = 0.f;
#pragma unroll
            for (int g2 = 0; g2 < 16; ++g2) a += red[g2][tid];
            S[tid] = a;
        }
        __syncthreads();
        if (tid < 32) {
            float a = 0.f;
#pragma unroll
            for (int k = 0; k < 64; ++k) a = fmaf(S[k], wgr[k * 32 + tid], a);
            gsf[tid] = a;
        }
        __syncthreads();
        float b = bC0[tid];
#pragma unroll
        for (int j = 0; j < 32; ++j) b = fmaf(gsf[j], Wih_c[tid * 64 + 32 + j], b);
        bias_c[tid] = b;
    }
}

// ---------------- cell LSTM step + outputs ----------------
__global__ __launch_bounds__(256) void k_cell(
    const float* __restrict__ frame,               // [N][2]
    const float* __restrict__ Wdy, const float* __restrict__ bdy,  // [32][2],[32]
    const ushort* __restrict__ Wc,                 // [256][160] bf16
    const float* __restrict__ bias_c,              // [256] (incl. S-fold)
    const ushort* __restrict__ ghb,                // [N][64] bf16 (gh2 of step t)
    float* __restrict__ cc,                        // [N][64] f32 live state
    ushort* __restrict__ chb,                      // [N][64] bf16 live state
    float* __restrict__ chf,                       // [N][64] f32 (iff last)
    const float* __restrict__ Wout, const float* __restrict__ bo5, // [5][64],[5]
    float* __restrict__ outp,                      // [N][5]
    int last)
{
    const int wave = threadIdx.x >> 6, lane = threadIdx.x & 63;
    const int c = lane & 15, g4 = lane >> 4;
    const int nbase = blockIdx.x * NPB + wave * 16;

    // ---- A fragments ----
    const int na = nbase + c;
    const float f0 = frame[2 * na], f1 = frame[2 * na + 1];
    bf16x8 a0, a1, a2, a3, a4;
    {
#pragma unroll
        for (int j = 0; j < 8; ++j) {
            int k = g4 * 8 + j;
            float v = fmaf(f1, Wdy[2 * k + 1], fmaf(f0, Wdy[2 * k], bdy[k]));
            a0[j] = (short)f2b(fmaxf(v, 0.f));
        }
        a1 = *(const bf16x8*)(ghb + na * 64 + g4 * 8);
        a2 = *(const bf16x8*)(ghb + na * 64 + 32 + g4 * 8);
        a3 = *(const bf16x8*)(chb + na * 64 + g4 * 8);
        a4 = *(const bf16x8*)(chb + na * 64 + 32 + g4 * 8);
    }

    float po[4][OUTx];
#pragma unroll
    for (int r = 0; r < 4; ++r)
#pragma unroll
        for (int o = 0; o < OUTx; ++o) po[r][o] = 0.f;

#pragma unroll
    for (int q = 0; q < 4; ++q) {
        f32x4 acc[4];
#pragma unroll
        for (int g = 0; g < 4; ++g) {
            acc[g] = (f32x4){0.f, 0.f, 0.f, 0.f};
            const int colb = 16 * (4 * g + q);
            const ushort* wp = Wc + (colb + c) * KC + g4 * 8;
            bf16x8 b0 = *(const bf16x8*)(wp);
            bf16x8 b1 = *(const bf16x8*)(wp + 32);
            bf16x8 b2 = *(const bf16x8*)(wp + 64);
            bf16x8 b3 = *(const bf16x8*)(wp + 96);
            bf16x8 b4 = *(const bf16x8*)(wp + 128);
            acc[g] = __builtin_amdgcn_mfma_f32_16x16x32_bf16(a0, b0, acc[g], 0, 0, 0);
            acc[g] = __builtin_amdgcn_mfma_f32_16x16x32_bf16(a1, b1, acc[g], 0, 0, 0);
            acc[g] = __builtin_amdgcn_mfma_f32_16x16x32_bf16(a2, b2, acc[g], 0, 0, 0);
            acc[g] = __builtin_amdgcn_mfma_f32_16x16x32_bf16(a3, b3, acc[g], 0, 0, 0);
            acc[g] = __builtin_amdgcn_mfma_f32_16x16x32_bf16(a4, b4, acc[g], 0, 0, 0);
        }
        const int d = 16 * q + c;
        const float bi = bias_c[d], bf = bias_c[64 + d],
                    bg = bias_c[128 + d], bov = bias_c[192 + d];
        const float w0 = Wout[0 * 64 + d], w1 = Wout[1 * 64 + d],
                    w2 = Wout[2 * 64 + d], w3 = Wout[3 * 64 + d],
                    w4 = Wout[4 * 64 + d];
#pragma unroll
        for (int r = 0; r < 4; ++r) {
            const int n = nbase + 4 * g4 + r;
            const float ai = acc[0][r] + bi, af = acc[1][r] + bf,
                        ag = acc[2][r] + bg, ao = acc[3][r] + bov;
            const float cp = cc[n * 64 + d];
            const float c2 = fmaf(sigm(af), cp, sigm(ai) * tanh_fast(ag));
            cc[n * 64 + d] = c2;
            const float h2 = sigm(ao) * tanh_fast(c2);
            chb[n * 64 + d] = f2b(h2);
            if (last) chf[n * 64 + d] = h2;
            po[r][0] = fmaf(h2, w0, po[r][0]);
            po[r][1] = fmaf(h2, w1, po[r][1]);
            po[r][2] = fmaf(h2, w2, po[r][2]);
            po[r][3] = fmaf(h2, w3, po[r][3]);
            po[r][4] = fmaf(h2, w4, po[r][4]);
        }
    }
    // reduce over c (dims) within each g4 group; lane c==0 stores
#pragma unroll
    for (int r = 0; r < 4; ++r)
#pragma unroll
        for (int o = 0; o < OUTx; ++o) {
            float v = po[r][o];
            v += __shfl_xor(v, 1);
            v += __shfl_xor(v, 2);
            v += __shfl_xor(v, 4);
            v += __shfl_xor(v, 8);
            if (c == 0) outp[(nbase + 4 * g4 + r) * OUTx + o] = v + bo5[o];
        }
}

extern "C" void kernel_launch(void* const* d_in, const int* in_sizes, int n_in,
                              void* d_out, int out_size, void* d_ws, size_t ws_size,
                              hipStream_t stream) {
    const float* input   = (const float*)d_in[0];   // [S][N][2]
    const float* cell_h0 = (const float*)d_in[1];
    const float* cell_c0 = (const float*)d_in[2];
    const float* graph_h0= (const float*)d_in[3];
    const float* graph_c0= (const float*)d_in[4];
    const float* W_dyn   = (const float*)d_in[5];
    const float* b_dyn   = (const float*)d_in[6];
    const float* W_gemb  = (const float*)d_in[7];
    const float* b_gemb  = (const float*)d_in[8];
    const float* Wih_g   = (const float*)d_in[9];
    const float* Whh_g   = (const float*)d_in[10];
    const float* bih_g   = (const float*)d_in[11];
    const float* bhh_g   = (const float*)d_in[12];
    const float* w_graph = (const float*)d_in[13];
    const float* Wih_c   = (const float*)d_in[14];
    const float* Whh_c   = (const float*)d_in[15];
    const float* bih_c   = (const float*)d_in[16];
    const float* bhh_c   = (const float*)d_in[17];
    const float* W_out   = (const float*)d_in[18];
    const float* b_out   = (const float*)d_in[19];

    float* out0 = (float*)d_out;                        // [S][N][5]
    float* chf = out0 + (size_t)Sx * Nx * OUTx;         // [N][64] final ch
    float* cc  = chf + (size_t)Nx * CHx;                // [N][64] live cc
    float* ghf = cc  + (size_t)Nx * CHx;                // [N][64] final gh
    float* gc  = ghf + (size_t)Nx * GHx;                // [N][64] live gc

    char* w = (char*)d_ws;
    ushort* ghb     = (ushort*)w;                 w += (size_t)Nx * 64 * 2;   // 8 MB
    ushort* chb     = (ushort*)w;                 w += (size_t)Nx * 64 * 2;   // 8 MB
    float*  partials= (float*)w;                  w += (size_t)GB * 64 * 4;   // 256 KB
    ushort* Wg      = (ushort*)w;                 w += 256 * KG * 2;
    ushort* Wc      = (ushort*)w;                 w += 256 * KC * 2;
    float*  bsum_g  = (float*)w;                  w += 256 * 4;
    float*  bC0     = (float*)w;                  w += 256 * 4;
    float*  bias_c  = (float*)w;                  w += 256 * 4;
    int*    counters= (int*)w;                    w += Sx * 4;

    hipMemcpyAsync(gc, graph_c0, (size_t)Nx * GHx * sizeof(float), hipMemcpyDeviceToDevice, stream);
    hipMemcpyAsync(cc, cell_c0,  (size_t)Nx * CHx * sizeof(float), hipMemcpyDeviceToDevice, stream);

    k_prep<<<64, 256, 0, stream>>>(Wih_g, Whh_g, bih_g, bhh_g, w_graph,
                                   Wih_c, Whh_c, bih_c, bhh_c,
                                   Wg, Wc, bsum_g, bC0);
    k_init<<<(Nx * 64) / 256, 256, 0, stream>>>(graph_h0, cell_h0, ghb, chb, counters);

    for (int t = 0; t < Sx; ++t) {
        const float* frame = input + (size_t)t * Nx * 2;
        const int last = (t == Sx - 1);
        k_graph<<<GB, 256, 0, stream>>>(frame, W_gemb, b_gemb, Wg, bsum_g,
                                        gc, ghb, ghf, partials,
                                        w_graph, Wih_c, bC0, bias_c,
                                        counters + t, last);
        k_cell<<<GB, 256, 0, stream>>>(frame, W_dyn, b_dyn, Wc, bias_c, ghb,
                                       cc, chb, chf, W_out, b_out,
                                       out0 + (size_t)t * Nx * OUTx, last);
    }
}

// Round 4
// 1895.882 us; speedup vs baseline: 2.8656x; 2.8656x over previous
//
#include <hip/hip_runtime.h>

// GraphLSTM, one-kernel-per-step MFMA version. S=32, N=65536.
// k_step(i): [prologue: per-block redundant reduce of partials(i-1) -> bias_c
// in LDS]  +  cell LSTM step (i-1)  +  graph LSTM step (i).
// Global sync for the gh-sum comes from the kernel boundary (cheap single L2
// writeback) -- NO in-kernel fences/atomics (round-3 lesson: per-block
// __threadfence = per-block L2 writeback = disaster).
// Partials double-buffered, transposed [64][GRID] for coalesced reduce.
// h-states bf16 (ws); c-states f32 (d_out slots). graph_feat folded into the
// cell-gate K (per-node -gh@Wfold, bf16) + step bias (S@Wfold2, f32).

#define Sx    32
#define Nx    65536
#define DYNx  32
#define GHx   64
#define MATx  32
#define CHx   64
#define OUTx  5
#define TPB   512             // 8 waves
#define NPB   128             // nodes per block (8 waves x 16)
#define GRID  (Nx / NPB)      // 512 blocks
#define KG    96              // graph gates K: [gemb(32) | gh(64)]
#define KC    160             // cell gates K:  [dyn(32) | gh(64) | ch(64)]

typedef __attribute__((ext_vector_type(4))) float f32x4;
typedef __attribute__((ext_vector_type(8))) short bf16x8;
typedef unsigned short ushort;
typedef unsigned int uint;

__device__ __forceinline__ float sigm(float x) {
    return __frcp_rn(1.f + __expf(-x));
}
__device__ __forceinline__ float tanh_fast(float x) {
    return fmaf(-2.f, __frcp_rn(1.f + __expf(2.f * x)), 1.f);
}
__device__ __forceinline__ ushort f2b(float x) {
    uint u = __float_as_uint(x);
    u += 0x7fffu + ((u >> 16) & 1u);   // RNE
    return (ushort)(u >> 16);
}

// ---------------- weight prep (once per launch, parallel) ----------------
__global__ __launch_bounds__(256) void k_prep(
    const float* __restrict__ Wih_g, const float* __restrict__ Whh_g,
    const float* __restrict__ bih_g, const float* __restrict__ bhh_g,
    const float* __restrict__ wgr,
    const float* __restrict__ Wih_c, const float* __restrict__ Whh_c,
    const float* __restrict__ bih_c, const float* __restrict__ bhh_c,
    ushort* __restrict__ Wg, ushort* __restrict__ Wc,
    float* __restrict__ Wfold2,
    float* __restrict__ bsum_g, float* __restrict__ bC0)
{
    const int tid = blockIdx.x * 256 + threadIdx.x;
    const int nt = gridDim.x * 256;
    for (int idx = tid; idx < 256 * KG; idx += nt) {
        int col = idx / KG, k = idx % KG;
        float v = (k < 32) ? Wih_g[col * 32 + k] : Whh_g[col * 64 + (k - 32)];
        Wg[idx] = f2b(v);
    }
    for (int idx = tid; idx < 256 * KC; idx += nt) {
        int col = idx / KC, k = idx % KC;
        float v;
        if (k < 32) v = Wih_c[col * 64 + k];
        else if (k < 96) {
            int d = k - 32; float a = 0.f;
            for (int j = 0; j < 32; ++j)
                a = fmaf(wgr[d * 32 + j], Wih_c[col * 64 + 32 + j], a);
            v = -a;   // per-node part of loo is (-gh)
        } else v = Whh_c[col * 64 + (k - 96)];
        Wc[idx] = f2b(v);
    }
    // Wfold2[k][col] = sum_j wgr[k][j] * Wih_c[col][32+j]   (f32, for S-bias)
    for (int idx = tid; idx < 64 * 256; idx += nt) {
        int k = idx >> 8, col = idx & 255;
        float a = 0.f;
        for (int j = 0; j < 32; ++j)
            a = fmaf(wgr[k * 32 + j], Wih_c[col * 64 + 32 + j], a);
        Wfold2[idx] = a;
    }
    if (tid < 256) {
        bsum_g[tid] = bih_g[tid] + bhh_g[tid];
        bC0[tid]    = bih_c[tid] + bhh_c[tid];
    }
}

__global__ __launch_bounds__(256) void k_init(
    const float* __restrict__ gh0, const float* __restrict__ ch0,
    ushort* __restrict__ ghb, ushort* __restrict__ chb)
{
    const int i = blockIdx.x * 256 + threadIdx.x;
    ghb[i] = f2b(gh0[i]);
    chb[i] = f2b(ch0[i]);
}

// ---------------- fused per-step kernel ----------------
__global__ __launch_bounds__(TPB) void k_step(
    const float* __restrict__ frame_c,             // [N][2] frame(i-1)
    const float* __restrict__ frame_g,             // [N][2] frame(i)
    const float* __restrict__ pin,                 // [64][GRID] partials(i-1)
    float* __restrict__ pout,                      // [64][GRID] partials(i)
    // cell weights
    const float* __restrict__ Wdy, const float* __restrict__ bdy,
    const ushort* __restrict__ Wc,
    const float* __restrict__ Wfold2, const float* __restrict__ bC0,
    const float* __restrict__ Wout, const float* __restrict__ bo5,
    // graph weights
    const float* __restrict__ Wge, const float* __restrict__ bge,
    const ushort* __restrict__ Wg, const float* __restrict__ bsum_g,
    // states
    ushort* __restrict__ ghb, float* __restrict__ gc,
    ushort* __restrict__ chb, float* __restrict__ cc,
    float* __restrict__ ghf, float* __restrict__ chf,
    float* __restrict__ outp,                      // [N][5] step i-1
    int do_cell, int do_graph, int last_cell, int last_graph)
{
    const int tid = threadIdx.x;
    const int wave = tid >> 6, lane = tid & 63;
    const int c = lane & 15, g4 = lane >> 4;
    const int nbase = blockIdx.x * NPB + wave * 16;
    const int na = nbase + c;

    __shared__ float S_lds[GHx];
    __shared__ float bias_lds[256];
    __shared__ float wsum[8][GHx];

    // gh(i-1) fragments -- shared by cell phase (K 32..96) and graph phase
    bf16x8 a_gh0 = *(const bf16x8*)(ghb + na * 64 + g4 * 8);
    bf16x8 a_gh1 = *(const bf16x8*)(ghb + na * 64 + 32 + g4 * 8);

    if (do_cell) {
        // ---- prologue: reduce partials -> S -> cell-gate step bias ----
        {
            const int d = tid >> 3, j = tid & 7;
            const f32x4* pp = (const f32x4*)(pin + d * GRID + j * 64);
            f32x4 a4 = (f32x4){0.f, 0.f, 0.f, 0.f};
#pragma unroll
            for (int k2 = 0; k2 < 16; ++k2) a4 += pp[k2];
            float s = (a4[0] + a4[1]) + (a4[2] + a4[3]);
            s += __shfl_xor(s, 1);
            s += __shfl_xor(s, 2);
            s += __shfl_xor(s, 4);
            if (j == 0) S_lds[d] = s;
        }
        __syncthreads();
        if (tid < 256) {
            float b = bC0[tid];
#pragma unroll
            for (int k = 0; k < 64; ++k)
                b = fmaf(S_lds[k], Wfold2[k * 256 + tid], b);
            bias_lds[tid] = b;
        }
        __syncthreads();

        // ---- cell LSTM step (i-1) ----
        const float f0 = frame_c[2 * na], f1 = frame_c[2 * na + 1];
        bf16x8 a0, a3, a4;
#pragma unroll
        for (int j = 0; j < 8; ++j) {
            int k = g4 * 8 + j;
            float v = fmaf(f1, Wdy[2 * k + 1], fmaf(f0, Wdy[2 * k], bdy[k]));
            a0[j] = (short)f2b(fmaxf(v, 0.f));
        }
        a3 = *(const bf16x8*)(chb + na * 64 + g4 * 8);
        a4 = *(const bf16x8*)(chb + na * 64 + 32 + g4 * 8);

        float po[4][OUTx];
#pragma unroll
        for (int r = 0; r < 4; ++r)
#pragma unroll
            for (int o = 0; o < OUTx; ++o) po[r][o] = 0.f;

#pragma unroll
        for (int q = 0; q < 4; ++q) {
            f32x4 acc[4];
#pragma unroll
            for (int g = 0; g < 4; ++g) {
                acc[g] = (f32x4){0.f, 0.f, 0.f, 0.f};
                const int colb = 16 * (4 * g + q);
                const ushort* wp = Wc + (colb + c) * KC + g4 * 8;
                bf16x8 b0 = *(const bf16x8*)(wp);
                bf16x8 b1 = *(const bf16x8*)(wp + 32);
                bf16x8 b2 = *(const bf16x8*)(wp + 64);
                bf16x8 b3 = *(const bf16x8*)(wp + 96);
                bf16x8 b4 = *(const bf16x8*)(wp + 128);
                acc[g] = __builtin_amdgcn_mfma_f32_16x16x32_bf16(a0, b0, acc[g], 0, 0, 0);
                acc[g] = __builtin_amdgcn_mfma_f32_16x16x32_bf16(a_gh0, b1, acc[g], 0, 0, 0);
                acc[g] = __builtin_amdgcn_mfma_f32_16x16x32_bf16(a_gh1, b2, acc[g], 0, 0, 0);
                acc[g] = __builtin_amdgcn_mfma_f32_16x16x32_bf16(a3, b3, acc[g], 0, 0, 0);
                acc[g] = __builtin_amdgcn_mfma_f32_16x16x32_bf16(a4, b4, acc[g], 0, 0, 0);
            }
            const int d = 16 * q + c;
            const float bi = bias_lds[d], bf = bias_lds[64 + d],
                        bg = bias_lds[128 + d], bov = bias_lds[192 + d];
            const float w0 = Wout[0 * 64 + d], w1 = Wout[1 * 64 + d],
                        w2 = Wout[2 * 64 + d], w3 = Wout[3 * 64 + d],
                        w4 = Wout[4 * 64 + d];
#pragma unroll
            for (int r = 0; r < 4; ++r) {
                const int n = nbase + 4 * g4 + r;
                const float ai = acc[0][r] + bi, af = acc[1][r] + bf,
                            ag = acc[2][r] + bg, ao = acc[3][r] + bov;
                const float cp = cc[n * 64 + d];
                const float c2 = fmaf(sigm(af), cp, sigm(ai) * tanh_fast(ag));
                cc[n * 64 + d] = c2;
                const float h2 = sigm(ao) * tanh_fast(c2);
                chb[n * 64 + d] = f2b(h2);
                if (last_cell) chf[n * 64 + d] = h2;
                po[r][0] = fmaf(h2, w0, po[r][0]);
                po[r][1] = fmaf(h2, w1, po[r][1]);
                po[r][2] = fmaf(h2, w2, po[r][2]);
                po[r][3] = fmaf(h2, w3, po[r][3]);
                po[r][4] = fmaf(h2, w4, po[r][4]);
            }
        }
#pragma unroll
        for (int r = 0; r < 4; ++r)
#pragma unroll
            for (int o = 0; o < OUTx; ++o) {
                float v = po[r][o];
                v += __shfl_xor(v, 1);
                v += __shfl_xor(v, 2);
                v += __shfl_xor(v, 4);
                v += __shfl_xor(v, 8);
                if (c == 0) outp[(nbase + 4 * g4 + r) * OUTx + o] = v + bo5[o];
            }
    }

    if (do_graph) {
        // ---- graph LSTM step (i) ----
        const float f0 = frame_g[2 * na], f1 = frame_g[2 * na + 1];
        bf16x8 a0;
#pragma unroll
        for (int j = 0; j < 8; ++j) {
            int k = g4 * 8 + j;
            float v = fmaf(f1, Wge[2 * k + 1], fmaf(f0, Wge[2 * k], bge[k]));
            a0[j] = (short)f2b(fmaxf(v, 0.f));
        }

        float hsq[4];
#pragma unroll
        for (int q = 0; q < 4; ++q) {
            f32x4 acc[4];
#pragma unroll
            for (int g = 0; g < 4; ++g) {
                acc[g] = (f32x4){0.f, 0.f, 0.f, 0.f};
                const int colb = 16 * (4 * g + q);
                const ushort* wp = Wg + (colb + c) * KG + g4 * 8;
                bf16x8 b0 = *(const bf16x8*)(wp);
                bf16x8 b1 = *(const bf16x8*)(wp + 32);
                bf16x8 b2 = *(const bf16x8*)(wp + 64);
                acc[g] = __builtin_amdgcn_mfma_f32_16x16x32_bf16(a0, b0, acc[g], 0, 0, 0);
                acc[g] = __builtin_amdgcn_mfma_f32_16x16x32_bf16(a_gh0, b1, acc[g], 0, 0, 0);
                acc[g] = __builtin_amdgcn_mfma_f32_16x16x32_bf16(a_gh1, b2, acc[g], 0, 0, 0);
            }
            const int d = 16 * q + c;
            const float bi = bsum_g[d], bf = bsum_g[64 + d],
                        bg = bsum_g[128 + d], bo = bsum_g[192 + d];
            float s_r = 0.f;
#pragma unroll
            for (int r = 0; r < 4; ++r) {
                const int n = nbase + 4 * g4 + r;
                const float ai = acc[0][r] + bi, af = acc[1][r] + bf,
                            ag = acc[2][r] + bg, ao = acc[3][r] + bo;
                const float cp = gc[n * 64 + d];
                const float c2 = fmaf(sigm(af), cp, sigm(ai) * tanh_fast(ag));
                gc[n * 64 + d] = c2;
                const float h2 = sigm(ao) * tanh_fast(c2);
                ghb[n * 64 + d] = f2b(h2);
                if (last_graph) ghf[n * 64 + d] = h2;
                s_r += h2;
            }
            hsq[q] = s_r;
        }
#pragma unroll
        for (int q = 0; q < 4; ++q) {
            float v = hsq[q];
            v += __shfl_xor(v, 16);
            v += __shfl_xor(v, 32);
            hsq[q] = v;
        }
        __syncthreads();   // all reads of S_lds/wsum region done (cell phase)
        if (g4 == 0) {
#pragma unroll
            for (int q = 0; q < 4; ++q) wsum[wave][16 * q + c] = hsq[q];
        }
        __syncthreads();
        if (tid < 64) {
            float a = 0.f;
#pragma unroll
            for (int w8 = 0; w8 < 8; ++w8) a += wsum[w8][tid];
            pout[tid * GRID + blockIdx.x] = a;   // transposed [64][GRID]
        }
    }
}

extern "C" void kernel_launch(void* const* d_in, const int* in_sizes, int n_in,
                              void* d_out, int out_size, void* d_ws, size_t ws_size,
                              hipStream_t stream) {
    const float* input   = (const float*)d_in[0];   // [S][N][2]
    const float* cell_h0 = (const float*)d_in[1];
    const float* cell_c0 = (const float*)d_in[2];
    const float* graph_h0= (const float*)d_in[3];
    const float* graph_c0= (const float*)d_in[4];
    const float* W_dyn   = (const float*)d_in[5];
    const float* b_dyn   = (const float*)d_in[6];
    const float* W_gemb  = (const float*)d_in[7];
    const float* b_gemb  = (const float*)d_in[8];
    const float* Wih_g   = (const float*)d_in[9];
    const float* Whh_g   = (const float*)d_in[10];
    const float* bih_g   = (const float*)d_in[11];
    const float* bhh_g   = (const float*)d_in[12];
    const float* w_graph = (const float*)d_in[13];
    const float* Wih_c   = (const float*)d_in[14];
    const float* Whh_c   = (const float*)d_in[15];
    const float* bih_c   = (const float*)d_in[16];
    const float* bhh_c   = (const float*)d_in[17];
    const float* W_out   = (const float*)d_in[18];
    const float* b_out   = (const float*)d_in[19];

    float* out0 = (float*)d_out;                        // [S][N][5]
    float* chf = out0 + (size_t)Sx * Nx * OUTx;         // [N][64] final ch
    float* cc  = chf + (size_t)Nx * CHx;                // [N][64] live cc
    float* ghf = cc  + (size_t)Nx * CHx;                // [N][64] final gh
    float* gc  = ghf + (size_t)Nx * GHx;                // [N][64] live gc

    char* w = (char*)d_ws;
    ushort* ghb     = (ushort*)w;                 w += (size_t)Nx * 64 * 2;   // 8 MB
    ushort* chb     = (ushort*)w;                 w += (size_t)Nx * 64 * 2;   // 8 MB
    float*  pbuf    = (float*)w;                  w += (size_t)2 * 64 * GRID * 4;
    ushort* Wg      = (ushort*)w;                 w += 256 * KG * 2;
    ushort* Wc      = (ushort*)w;                 w += 256 * KC * 2;
    float*  Wfold2  = (float*)w;                  w += 64 * 256 * 4;
    float*  bsum_g  = (float*)w;                  w += 256 * 4;
    float*  bC0     = (float*)w;                  w += 256 * 4;

    hipMemcpyAsync(gc, graph_c0, (size_t)Nx * GHx * sizeof(float), hipMemcpyDeviceToDevice, stream);
    hipMemcpyAsync(cc, cell_c0,  (size_t)Nx * CHx * sizeof(float), hipMemcpyDeviceToDevice, stream);

    k_prep<<<64, 256, 0, stream>>>(Wih_g, Whh_g, bih_g, bhh_g, w_graph,
                                   Wih_c, Whh_c, bih_c, bhh_c,
                                   Wg, Wc, Wfold2, bsum_g, bC0);
    k_init<<<(Nx * 64) / 256, 256, 0, stream>>>(graph_h0, cell_h0, ghb, chb);

    for (int i = 0; i <= Sx; ++i) {
        const int do_cell    = (i >= 1);
        const int do_graph   = (i <= Sx - 1);
        const int last_cell  = (i == Sx);
        const int last_graph = (i == Sx - 1);
        const float* frame_c = do_cell  ? input + (size_t)(i - 1) * Nx * 2 : input;
        const float* frame_g = do_graph ? input + (size_t)i * Nx * 2       : input;
        float* pin  = pbuf + (size_t)((i + 1) & 1) * 64 * GRID;
        float* pout = pbuf + (size_t)(i & 1) * 64 * GRID;
        float* outp = out0 + (size_t)(do_cell ? (i - 1) : 0) * Nx * OUTx;
        k_step<<<GRID, TPB, 0, stream>>>(frame_c, frame_g, pin, pout,
                                         W_dyn, b_dyn, Wc, Wfold2, bC0, W_out, b_out,
                                         W_gemb, b_gemb, Wg, bsum_g,
                                         ghb, gc, chb, cc, ghf, chf, outp,
                                         do_cell, do_graph, last_cell, last_graph);
    }
}